// Round 2
// baseline (10507.416 us; speedup 1.0000x reference)
//
#include <hip/hip_runtime.h>
#include <hip/hip_fp16.h>
#include <math.h>

// ---------------------------------------------------------------------------
// ODERGRU pipeline for MI355X.
//  K1: einsum -> h1 (3200,96,29)
//  K2: conv1d 96->96 k5 + bias -> h2 + BN partials
//  K3: BN1 reduce (parallel, f64 tree)
//  K4: conv1d 96->16 k5 (BN1+lrelu on load) -> h3 + BN2 partials
//  K5: BN2 reduce
//  K6: OAS + Cholesky -> x_d, x_o
//  K0: pack ODE/GRU weights f32 -> f16x2 (into dead h2 region)
//  K7: per-batch-row scan; ODE weights resident in VGPRs+LDS (f16 pairs)
// ---------------------------------------------------------------------------

#define BB 64
#define NIMG 3200

__device__ __forceinline__ float sigm(float x) { return 1.f / (1.f + expf(-x)); }

// ------------------------------ K1: filterbank ------------------------------
__global__ __launch_bounds__(256) void k1_fb(const float* __restrict__ x,
                                             const float* __restrict__ fw,
                                             const float* __restrict__ st,
                                             float* __restrict__ h1) {
  __shared__ __align__(16) float ws[129 * 32];
  __shared__ __align__(16) float xs[129 * 32];
  const int tid = threadIdx.x;
  const int n = blockIdx.x;
  const float* xp = x + (size_t)n * 11223;

  for (int i = tid; i < 4128; i += 256) ws[i] = fw[i] * st[i];

  float acc[4][4];
#pragma unroll
  for (int i = 0; i < 4; ++i)
#pragma unroll
    for (int j = 0; j < 4; ++j) acc[i][j] = 0.f;

  const int c = tid / 64;
  const int rem = tid % 64;
  const int m0 = (rem / 8) * 4;
  const int t0 = (rem % 8) * 4;

  for (int fc = 0; fc < 3; ++fc) {
    __syncthreads();
    for (int i = tid; i < 3741; i += 256) {
      int cc = i / 1247;
      int r = i - cc * 1247;
      int f = r / 29;
      int t = r - f * 29;
      xs[(cc * 43 + f) * 32 + t] = xp[cc * 3741 + (fc * 43 + f) * 29 + t];
    }
    for (int i = tid; i < 129; i += 256) {
      xs[i * 32 + 29] = 0.f; xs[i * 32 + 30] = 0.f; xs[i * 32 + 31] = 0.f;
    }
    __syncthreads();
    if (tid < 192) {
      const float* xb = xs + (c * 43) * 32 + t0;
      const float* wb = ws + (fc * 43) * 32 + m0;
      for (int f = 0; f < 43; ++f) {
        float4 xv = *(const float4*)(xb + f * 32);
        float4 wv = *(const float4*)(wb + f * 32);
        float xa[4] = {xv.x, xv.y, xv.z, xv.w};
        float wa[4] = {wv.x, wv.y, wv.z, wv.w};
#pragma unroll
        for (int i = 0; i < 4; ++i)
#pragma unroll
          for (int j = 0; j < 4; ++j) acc[i][j] += wa[i] * xa[j];
      }
    }
  }
  if (tid < 192) {
    const int nt = (t0 == 28) ? 1 : 4;
    for (int i = 0; i < 4; ++i)
      for (int j = 0; j < nt; ++j)
        h1[(size_t)n * 2784 + (size_t)(c * 32 + m0 + i) * 29 + (t0 + j)] = acc[i][j];
  }
}

// ------------------------------ K2: conv1 ------------------------------
__global__ __launch_bounds__(256) void k2_conv1(const float* __restrict__ h1,
                                                const float* __restrict__ w,
                                                const float* __restrict__ bias,
                                                float* __restrict__ h2,
                                                float* __restrict__ part1) {
  __shared__ __align__(16) float ins[2 * 96 * 32];
  __shared__ __align__(16) float wls[96 * 81];
  const int tid = threadIdx.x;
  const int wg = blockIdx.x;

  for (int i = tid; i < 2 * 2784; i += 256) {
    int img = i / 2784;
    int e = i - img * 2784;
    int ci = e / 29;
    int t = e - ci * 29;
    ins[img * 3072 + ci * 32 + t] = h1[(size_t)(wg * 2 + img) * 2784 + e];
  }

  const int img = tid / 96;
  const int co = tid - img * 96;
  float acc[25];
#pragma unroll
  for (int t = 0; t < 25; ++t) acc[t] = 0.f;

  for (int cc = 0; cc < 6; ++cc) {
    __syncthreads();
    for (int i = tid; i < 7680; i += 256) {
      int cw = i / 80;
      int r = i - cw * 80;
      wls[cw * 81 + r] = w[cw * 480 + cc * 80 + r];
    }
    __syncthreads();
    if (tid < 192) {
      for (int ci = 0; ci < 16; ++ci) {
        float xv[29];
#pragma unroll
        for (int j = 0; j < 29; ++j) xv[j] = ins[img * 3072 + (cc * 16 + ci) * 32 + j];
        float wv[5];
#pragma unroll
        for (int d = 0; d < 5; ++d) wv[d] = wls[co * 81 + ci * 5 + d];
#pragma unroll
        for (int t = 0; t < 25; ++t) {
          float s = acc[t];
#pragma unroll
          for (int d = 0; d < 5; ++d) s += xv[t + d] * wv[d];
          acc[t] = s;
        }
      }
    }
  }
  if (tid < 192) {
    const int n = wg * 2 + img;
    const float bval = bias[co];
    float s1 = 0.f, s2 = 0.f;
    for (int t = 0; t < 25; ++t) {
      float v = acc[t] + bval;
      h2[(size_t)n * 2400 + co * 25 + t] = v;
      s1 += v;
      s2 += v * v;
    }
    part1[((size_t)n * 96 + co) * 2 + 0] = s1;
    part1[((size_t)n * 96 + co) * 2 + 1] = s2;
  }
}

// ------------------------------ K3/K5: BN reduce (parallel) -----------------
__global__ __launch_bounds__(256) void k3_bn1(const float* __restrict__ part,
                                              const float* __restrict__ gg,
                                              const float* __restrict__ be,
                                              float* __restrict__ ab) {
  __shared__ double sd[256], sq[256];
  const int c = blockIdx.x;       // 96
  const int t = threadIdx.x;
  double s = 0.0, q = 0.0;
  for (int n = t; n < NIMG; n += 256) {
    s += (double)part[((size_t)n * 96 + c) * 2 + 0];
    q += (double)part[((size_t)n * 96 + c) * 2 + 1];
  }
  sd[t] = s; sq[t] = q;
  __syncthreads();
  for (int off = 128; off > 0; off >>= 1) {
    if (t < off) { sd[t] += sd[t + off]; sq[t] += sq[t + off]; }
    __syncthreads();
  }
  if (t == 0) {
    double mu = sd[0] / 80000.0;
    double var = sq[0] / 80000.0 - mu * mu;
    float A = (float)((double)gg[c] / sqrt(var + 1e-5));
    ab[c * 2 + 0] = A;
    ab[c * 2 + 1] = (float)((double)be[c] - mu * (double)A);
  }
}

__global__ __launch_bounds__(256) void k5_bn2(const float* __restrict__ part,
                                              const float* __restrict__ gg,
                                              const float* __restrict__ be,
                                              float* __restrict__ ab) {
  __shared__ double sd[256], sq[256];
  const int c = blockIdx.x;       // 16
  const int t = threadIdx.x;
  double s = 0.0, q = 0.0;
  for (int n = t; n < 800; n += 256) {
    s += (double)part[((size_t)n * 16 + c) * 2 + 0];
    q += (double)part[((size_t)n * 16 + c) * 2 + 1];
  }
  sd[t] = s; sq[t] = q;
  __syncthreads();
  for (int off = 128; off > 0; off >>= 1) {
    if (t < off) { sd[t] += sd[t + off]; sq[t] += sq[t + off]; }
    __syncthreads();
  }
  if (t == 0) {
    double mu = sd[0] / 67200.0;
    double var = sq[0] / 67200.0 - mu * mu;
    float A = (float)((double)gg[c] / sqrt(var + 1e-5));
    ab[c * 2 + 0] = A;
    ab[c * 2 + 1] = (float)((double)be[c] - mu * (double)A);
  }
}

// ------------------------------ K4: conv2 ------------------------------
__global__ __launch_bounds__(256) void k4_conv2(const float* __restrict__ h2,
                                                const float* __restrict__ w,
                                                const float* __restrict__ bias,
                                                const float* __restrict__ bn1,
                                                float* __restrict__ h3,
                                                float* __restrict__ part2) {
  __shared__ __align__(16) float ins[4 * 96 * 26];
  __shared__ __align__(16) float wls[16 * 241];
  __shared__ float A1s[96], B1s[96];
  __shared__ float red[16 * 16 * 2];
  const int tid = threadIdx.x;
  const int wg = blockIdx.x;

  if (tid < 96) {
    A1s[tid] = bn1[tid * 2 + 0];
    B1s[tid] = bn1[tid * 2 + 1];
  }
  __syncthreads();
  for (int i = tid; i < 9600; i += 256) {
    int img = i / 2400;
    int e = i - img * 2400;
    int ci = e / 25;
    int t = e - ci * 25;
    float v = h2[(size_t)(wg * 4 + img) * 2400 + e];
    v = A1s[ci] * v + B1s[ci];
    v = (v >= 0.f) ? v : 0.01f * v;
    ins[img * 2496 + ci * 26 + t] = v;
  }
  for (int i = tid; i < 4 * 96; i += 256) ins[(i / 96) * 2496 + (i % 96) * 26 + 25] = 0.f;

  const int img = tid >> 6;
  const int co = (tid >> 2) & 15;
  const int tg = tid & 3;
  const int t0s[4] = {0, 6, 11, 16};
  const int t0 = t0s[tg];
  const int tl = (tg == 0) ? 6 : 5;
  float acc[6] = {0.f, 0.f, 0.f, 0.f, 0.f, 0.f};

  for (int cc = 0; cc < 2; ++cc) {
    __syncthreads();
    for (int i = tid; i < 3840; i += 256) {
      int cw = i / 240;
      int r = i - cw * 240;
      wls[cw * 241 + r] = w[cw * 480 + cc * 240 + r];
    }
    __syncthreads();
    for (int ci = 0; ci < 48; ++ci) {
      float xv[10];
#pragma unroll
      for (int j = 0; j < 10; ++j) xv[j] = ins[img * 2496 + (cc * 48 + ci) * 26 + t0 + j];
      float wv[5];
#pragma unroll
      for (int d = 0; d < 5; ++d) wv[d] = wls[co * 241 + ci * 5 + d];
#pragma unroll
      for (int t = 0; t < 6; ++t) {
        float s = acc[t];
#pragma unroll
        for (int d = 0; d < 5; ++d) s += xv[t + d] * wv[d];
        acc[t] = s;
      }
    }
  }
  const float bval = bias[co];
  float s1 = 0.f, s2 = 0.f;
  const int n = wg * 4 + img;
  for (int t = 0; t < 6; ++t) {
    if (t < tl) {
      float v = acc[t] + bval;
      h3[(size_t)n * 336 + co * 21 + t0 + t] = v;
      s1 += v;
      s2 += v * v;
    }
  }
  red[(co * 16 + img * 4 + tg) * 2 + 0] = s1;
  red[(co * 16 + img * 4 + tg) * 2 + 1] = s2;
  __syncthreads();
  if (tid < 16) {
    float s = 0.f, q = 0.f;
    for (int k = 0; k < 16; ++k) {
      s += red[(tid * 16 + k) * 2 + 0];
      q += red[(tid * 16 + k) * 2 + 1];
    }
    part2[((size_t)wg * 16 + tid) * 2 + 0] = s;
    part2[((size_t)wg * 16 + tid) * 2 + 1] = q;
  }
}

// ------------------------------ K6: OAS + Cholesky ------------------------------
__global__ __launch_bounds__(256) void k6_oas(const float* __restrict__ h3,
                                              const float* __restrict__ bn2,
                                              float* __restrict__ xd,
                                              float* __restrict__ xo) {
  __shared__ float X[4][21 * 17 + 3];
  __shared__ float A[4][16 * 17];
  __shared__ float mcol[4][16];
  const int tid = threadIdx.x;
  const int wid = tid >> 6;
  const int lane = tid & 63;
  const int n = blockIdx.x * 4 + wid;
  const float* hp = h3 + (size_t)n * 336;

  for (int e = lane; e < 336; e += 64) {
    int c = e / 21;
    int t = e - c * 21;
    float v = hp[e];
    v = bn2[c * 2 + 0] * v + bn2[c * 2 + 1];
    v = (v >= 0.f) ? v : 0.01f * v;
    X[wid][t * 17 + c] = v;
  }
  __syncthreads();
  if (lane < 16) {
    float s = 0.f;
    for (int t = 0; t < 21; ++t) s += X[wid][t * 17 + lane];
    mcol[wid][lane] = s * (1.f / 21.f);
  }
  __syncthreads();
  for (int e = lane; e < 336; e += 64) {
    int t = e / 16;
    int c = e - t * 16;
    X[wid][t * 17 + c] -= mcol[wid][c];
  }
  __syncthreads();

  float tr_p = 0.f, al_p = 0.f;
  float ent[3];
  int ei[3], ej[3], ne = 0;
  for (int e = lane; e < 136; e += 64) {
    int i = 0, e2 = e;
    while (e2 >= 16 - i) { e2 -= 16 - i; i++; }
    int j = i + e2;
    float s = 0.f;
    for (int t = 0; t < 21; ++t) s += X[wid][t * 17 + i] * X[wid][t * 17 + j];
    s *= (1.f / 20.f);
    ent[ne] = s; ei[ne] = i; ej[ne] = j; ne++;
    if (i == j) tr_p += s;
    al_p += s * s * ((i == j) ? 1.f : 2.f);
  }
  for (int m = 1; m < 64; m <<= 1) {
    tr_p += __shfl_xor(tr_p, m);
    al_p += __shfl_xor(al_p, m);
  }
  const float mu = tr_p * (1.f / 16.f);
  const float alpha = al_p * (1.f / 256.f);
  const float num = alpha + mu * mu;
  const float den = 22.f * (alpha - mu * mu * (1.f / 16.f));
  const float shr = (den == 0.f) ? 1.f : fminf(num / den, 1.f);
  for (int q = 0; q < ne; ++q) {
    float c = (1.f - shr) * ent[q] + ((ei[q] == ej[q]) ? shr * mu : 0.f);
    A[wid][ei[q] * 17 + ej[q]] = c;
    A[wid][ej[q] * 17 + ei[q]] = c;
  }
  __syncthreads();

  for (int k = 0; k < 16; ++k) {
    float akk = A[wid][k * 17 + k];
    __syncthreads();
    float d = sqrtf(akk);
    float rd = 1.f / d;
    if (lane == k) A[wid][k * 17 + k] = d;
    if (lane > k && lane < 16) A[wid][lane * 17 + k] *= rd;
    __syncthreads();
    if (lane > k && lane < 16) {
      float Lik = A[wid][lane * 17 + k];
      for (int j = k + 1; j <= lane; ++j) A[wid][lane * 17 + j] -= Lik * A[wid][j * 17 + k];
    }
    __syncthreads();
  }
  if (lane < 16) xd[(size_t)n * 16 + lane] = A[wid][lane * 17 + lane];
  for (int p = lane; p < 120; p += 64) {
    int i = 1, p2 = p;
    while (p2 >= i) { p2 -= i; i++; }
    xo[(size_t)n * 120 + p] = A[wid][i * 17 + p2];
  }
}

// ------------------------------ K0: weight pack (f32 -> f16x2) --------------
// dst u32 layout: [0,17408) w0p [p*256+j], [17408,50176) w1p, [50176,82944) w2p,
// [82944,100352) w3p [p*136+c], [100352,121952) wxop [p*360+c], [121952,143552) whop
#define PK_TOT 143552
__global__ __launch_bounds__(256) void k0_pack(const float* __restrict__ w0,
                                               const float* __restrict__ w1,
                                               const float* __restrict__ w2,
                                               const float* __restrict__ w3,
                                               const float* __restrict__ wxo,
                                               const float* __restrict__ who,
                                               uint32_t* __restrict__ dst) {
  int i = blockIdx.x * 256 + threadIdx.x;
  if (i >= PK_TOT) return;
  float a, bf;
  if (i < 17408) {
    int p = i >> 8, j = i & 255;
    a = w0[(2 * p) * 256 + j]; bf = w0[(2 * p + 1) * 256 + j];
  } else if (i < 50176) {
    int t = i - 17408; int p = t >> 8, j = t & 255;
    a = w1[(2 * p) * 256 + j]; bf = w1[(2 * p + 1) * 256 + j];
  } else if (i < 82944) {
    int t = i - 50176; int p = t >> 8, j = t & 255;
    a = w2[(2 * p) * 256 + j]; bf = w2[(2 * p + 1) * 256 + j];
  } else if (i < 100352) {
    int t = i - 82944; int p = t / 136, c = t - p * 136;
    a = w3[(2 * p) * 136 + c]; bf = w3[(2 * p + 1) * 136 + c];
  } else if (i < 121952) {
    int t = i - 100352; int p = t / 360, c = t - p * 360;
    a = wxo[(2 * p) * 360 + c]; bf = wxo[(2 * p + 1) * 360 + c];
  } else {
    int t = i - 121952; int p = t / 360, c = t - p * 360;
    a = who[(2 * p) * 360 + c]; bf = who[(2 * p + 1) * 360 + c];
  }
  __half2 h = __floats2half2_rn(a, bf);
  dst[i] = *reinterpret_cast<uint32_t*>(&h);
}

// ------------------------------ K7: scan (resident weights) -----------------
#define W3LDSROWS 104
#define W3TAIL 24
__global__ __launch_bounds__(256, 1) void k7_scan(
    const float* __restrict__ xdv, const float* __restrict__ xov,
    const float* __restrict__ wxd, const float* __restrict__ whd,
    const float* __restrict__ bdv, const float* __restrict__ bov,
    const uint32_t* __restrict__ pk,
    const float* __restrict__ b0, const float* __restrict__ b1,
    const float* __restrict__ b2, const float* __restrict__ b3,
    const float* __restrict__ cw, const float* __restrict__ cbv,
    float* __restrict__ out) {
  __shared__ uint32_t w3s[W3LDSROWS * 136];          // 56576 B
  __shared__ __align__(16) float hc[136];
  __shared__ __align__(16) float bufA[256];
  __shared__ __align__(16) float bufB[256];
  __shared__ __align__(16) float xdl[16];
  __shared__ __align__(16) float xol[120];
  __shared__ __align__(16) float g[720];
  __shared__ __align__(16) float g2[96];
  const int j = threadIdx.x;
  const int b = blockIdx.x;

  const uint32_t* w0p = pk;
  const uint32_t* w1p = pk + 17408;
  const uint32_t* w2p = pk + 50176;
  const uint32_t* w3p = pk + 82944;
  const uint32_t* wxop = pk + 100352;
  const uint32_t* whop = pk + 121952;

  for (int i = j; i < W3LDSROWS * 136; i += 256) w3s[i] = w3p[i];

  uint32_t w0r[68], w1r[128], w2r[128], w3t[W3TAIL];
#pragma unroll
  for (int p = 0; p < 68; ++p) w0r[p] = w0p[p * 256 + j];
#pragma unroll
  for (int p = 0; p < 128; ++p) w1r[p] = w1p[p * 256 + j];
#pragma unroll
  for (int p = 0; p < 128; ++p) w2r[p] = w2p[p * 256 + j];
  const int jc = (j < 136) ? j : 0;
#pragma unroll
  for (int p = 0; p < W3TAIL; ++p) w3t[p] = w3p[(W3LDSROWS + p) * 136 + jc];

  const float bj0 = b0[j], bj1 = b1[j], bj2 = b2[j];
  const float bj3 = (j < 136) ? b3[j] : 0.f;

  if (j < 136) hc[j] = 0.f;
  __syncthreads();

#pragma unroll 1
  for (int s = 0; s < 50; ++s) {
    if (j < 16) xdl[j] = xdv[(size_t)(b * 50 + s) * 16 + j];
    if (j >= 16 && j < 136) xol[j - 16] = xov[(size_t)(b * 50 + s) * 120 + (j - 16)];
    // no barrier needed: first read of xdl/xol is in the gate phase, many barriers later

#pragma unroll 1
    for (int e = 0; e < 4; ++e) {
      // L1: hc(136) -> bufA(256) tanh
      {
        float acc = bj0;
        const float4* h4 = (const float4*)hc;
#pragma unroll
        for (int c = 0; c < 34; ++c) {
          float4 x4 = h4[c];
          float2 wa = __half22float2(*(const __half2*)&w0r[2 * c]);
          float2 wb = __half22float2(*(const __half2*)&w0r[2 * c + 1]);
          acc += x4.x * wa.x + x4.y * wa.y + x4.z * wb.x + x4.w * wb.y;
        }
        bufA[j] = tanhf(acc);
      }
      __syncthreads();
      // L2: bufA -> bufB tanh
      {
        float acc = bj1;
        const float4* a4 = (const float4*)bufA;
#pragma unroll
        for (int c = 0; c < 64; ++c) {
          float4 x4 = a4[c];
          float2 wa = __half22float2(*(const __half2*)&w1r[2 * c]);
          float2 wb = __half22float2(*(const __half2*)&w1r[2 * c + 1]);
          acc += x4.x * wa.x + x4.y * wa.y + x4.z * wb.x + x4.w * wb.y;
        }
        bufB[j] = tanhf(acc);
      }
      __syncthreads();
      // L3: bufB -> bufA tanh
      {
        float acc = bj2;
        const float4* a4 = (const float4*)bufB;
#pragma unroll
        for (int c = 0; c < 64; ++c) {
          float4 x4 = a4[c];
          float2 wa = __half22float2(*(const __half2*)&w2r[2 * c]);
          float2 wb = __half22float2(*(const __half2*)&w2r[2 * c + 1]);
          acc += x4.x * wa.x + x4.y * wa.y + x4.z * wb.x + x4.w * wb.y;
        }
        bufA[j] = tanhf(acc);
      }
      __syncthreads();
      // L4: bufA -> hc += 0.25*(...)
      if (j < 136) {
        float acc = bj3;
        const float4* a4 = (const float4*)bufA;
#pragma unroll
        for (int c = 0; c < 52; ++c) {
          float4 x4 = a4[c];
          float2 wa = __half22float2(*(const __half2*)&w3s[(2 * c) * 136 + j]);
          float2 wb = __half22float2(*(const __half2*)&w3s[(2 * c + 1) * 136 + j]);
          acc += x4.x * wa.x + x4.y * wa.y + x4.z * wb.x + x4.w * wb.y;
        }
#pragma unroll
        for (int c = 52; c < 64; ++c) {
          float4 x4 = a4[c];
          float2 wa = __half22float2(*(const __half2*)&w3t[2 * (c - 52)]);
          float2 wb = __half22float2(*(const __half2*)&w3t[2 * (c - 52) + 1]);
          acc += x4.x * wa.x + x4.y * wa.y + x4.z * wb.x + x4.w * wb.y;
        }
        hc[j] += 0.25f * acc;
      }
      __syncthreads();
    }

    // Gates: 720 o-dots (K=120, packed f16) + 96 d-dots (K=16, f32)
    for (int idx = j; idx < 816; idx += 256) {
      if (idx < 720) {
        const int which = (idx >= 360) ? 1 : 0;
        const int col = which ? idx - 360 : idx;
        const uint32_t* wp = (which ? whop : wxop) + col;
        const float2* s2 = which ? (const float2*)(hc + 16) : (const float2*)xol;
        float acc = 0.f;
#pragma unroll
        for (int p = 0; p < 60; ++p) {
          float2 xv = s2[p];
          float2 wv = __half22float2(*(const __half2*)&wp[p * 360]);
          acc += xv.x * wv.x + xv.y * wv.y;
        }
        g[idx] = acc;
      } else {
        const int jj = idx - 720;
        const int which = (jj >= 48) ? 1 : 0;
        const int col = which ? jj - 48 : jj;
        const float* W = which ? whd : wxd;
        float a = 0.f;
#pragma unroll
        for (int k = 0; k < 16; ++k) {
          float sv = which ? expf(hc[k]) : xdl[k];
          a += sv * fabsf(W[k * 48 + col]);
        }
        g2[jj] = a;
      }
    }
    __syncthreads();

    if (j < 120) {
      float r = sigm(g[j] + g[360 + j] + bov[j]);
      float z = sigm(g[120 + j] + g[480 + j] + bov[120 + j]);
      float ng = tanhf(g[240 + j] + r * g[600 + j] + bov[240 + j]);
      float ho = hc[16 + j];
      hc[16 + j] = ng + z * (ho - ng);
    } else if (j >= 128 && j < 144) {
      int t = j - 128;
      float ixr = g2[t], ixi = g2[16 + t], ixn = g2[32 + t];
      float hhr = g2[48 + t], hhi = g2[64 + t], hhn = g2[80 + t];
      float br = fabsf(bdv[t]), bi = fabsf(bdv[16 + t]), bn = fabsf(bdv[32 + t]);
      float r = sigm(br * ixr * hhr);
      float z = sigm(bi * ixi * hhi);
      float sp = bn * ixn * r * hhn;
      float ng = (sp > 20.f) ? sp : log1pf(expf(sp));
      float ldp = hc[t];
      hc[t] = z * ldp + (1.f - z) * logf(ng);
    }
    __syncthreads();
  }

  if (j < 5) {
    float a = cbv[j];
    for (int k = 0; k < 136; ++k) a += hc[k] * cw[k * 5 + j];
    out[(size_t)b * 5 + j] = a;
  }
}

// ------------------------------ launch ------------------------------
extern "C" void kernel_launch(void* const* d_in, const int* in_sizes, int n_in,
                              void* d_out, int out_size, void* d_ws, size_t ws_size,
                              hipStream_t stream) {
  const float* x       = (const float*)d_in[0];
  const float* fw      = (const float*)d_in[1];
  const float* s_tri   = (const float*)d_in[2];
  const float* conv1_w = (const float*)d_in[3];
  const float* conv1_b = (const float*)d_in[4];
  const float* bn1_g   = (const float*)d_in[5];
  const float* bn1_b   = (const float*)d_in[6];
  const float* conv2_w = (const float*)d_in[7];
  const float* conv2_b = (const float*)d_in[8];
  const float* bn2_g   = (const float*)d_in[9];
  const float* bn2_b   = (const float*)d_in[10];
  const float* wx_d    = (const float*)d_in[11];
  const float* wh_d    = (const float*)d_in[12];
  const float* bias_d  = (const float*)d_in[13];
  const float* wx_o    = (const float*)d_in[14];
  const float* wh_o    = (const float*)d_in[15];
  const float* bias_o  = (const float*)d_in[16];
  const float* ode_w0  = (const float*)d_in[17];
  const float* ode_b0  = (const float*)d_in[18];
  const float* ode_w1  = (const float*)d_in[19];
  const float* ode_b1  = (const float*)d_in[20];
  const float* ode_w2  = (const float*)d_in[21];
  const float* ode_b2  = (const float*)d_in[22];
  const float* ode_w3  = (const float*)d_in[23];
  const float* ode_b3  = (const float*)d_in[24];
  const float* cls_w   = (const float*)d_in[25];
  const float* cls_b   = (const float*)d_in[26];

  float* ws = (float*)d_ws;
  float* h1  = ws;                    // 8,908,800 floats (K1->K2), then dead
  float* h3  = ws;                    // 1,075,200 floats (K4->K6)
  float* xd  = ws + 1075200;          // 51,200
  float* xo  = ws + 1126400;          // 384,000
  float* h2  = ws + 8908800;          // 7,680,000 (K2->K4), then reused by K0
  float* p1  = ws + 16588800;         // 614,400
  float* bn1 = ws + 17203200;         // 192
  float* p2  = ws + 17203392;         // 25,600
  float* bn2 = ws + 17228992;         // 32
  uint32_t* pk = (uint32_t*)(ws + 8908800);  // packed weights (dead h2 region)

  hipLaunchKernelGGL(k1_fb,   dim3(NIMG),   dim3(256), 0, stream, x, fw, s_tri, h1);
  hipLaunchKernelGGL(k2_conv1,dim3(NIMG/2), dim3(256), 0, stream, h1, conv1_w, conv1_b, h2, p1);
  hipLaunchKernelGGL(k3_bn1,  dim3(96),     dim3(256), 0, stream, p1, bn1_g, bn1_b, bn1);
  hipLaunchKernelGGL(k4_conv2,dim3(NIMG/4), dim3(256), 0, stream, h2, conv2_w, conv2_b, bn1, h3, p2);
  hipLaunchKernelGGL(k5_bn2,  dim3(16),     dim3(256), 0, stream, p2, bn2_g, bn2_b, bn2);
  hipLaunchKernelGGL(k6_oas,  dim3(NIMG/4), dim3(256), 0, stream, h3, bn2, xd, xo);
  hipLaunchKernelGGL(k0_pack, dim3((PK_TOT + 255) / 256), dim3(256), 0, stream,
                     ode_w0, ode_w1, ode_w2, ode_w3, wx_o, wh_o, pk);
  hipLaunchKernelGGL(k7_scan, dim3(BB),     dim3(256), 0, stream,
                     xd, xo, wx_d, wh_d, bias_d, bias_o, pk,
                     ode_b0, ode_b1, ode_b2, ode_b3, cls_w, cls_b, (float*)d_out);
}